// Round 8
// baseline (435.703 us; speedup 1.0000x reference)
//
#include <hip/hip_runtime.h>

// FlowGuidedDCN: deformable 3x3 conv, stride=1, pad=1, dilation=1
// x: [B=8, C=3, H=512, W=512] f32 ; offsets: [B,18,H,W] f32 (dy,dx per tap)
// weight: [16,3,3,3] f32 ; bias: [16] f32 ; out: [B,16,H,W] f32

#define Bc 8
#define Cc 3
#define Hc 512
#define Wc 512
#define Oc 16
#define HWc (512 * 512)
#define KKc 9

// ---------- pass 1: x[B,C,H,W] -> xt[B,H,W,4] (channels-last, lane3=0) ----------
__global__ __launch_bounds__(256) void transpose_kernel(
    const float* __restrict__ x, float4* __restrict__ xt) {
  int pix = blockIdx.x * 256 + threadIdx.x;
  int b = pix >> 18;
  int hw = pix & (HWc - 1);
  const float* xb = x + b * (Cc * HWc) + hw;
  float4 v;
  v.x = xb[0];
  v.y = xb[HWc];
  v.z = xb[2 * HWc];
  v.w = 0.f;
  xt[pix] = v;
}

// ---------- pass 2: depth-2 pipelined taps, 3 slots, literal indices ----------
// R5: pin w/o headroom -> spill catastrophe. R7: depth-1 pin, VGPR 108, no
// spill, VALUBusy 64% -> ~50us exposed latency left. Here: depth-2 (consume
// tap k behind preps of k+1,k+2 => ~2 taps of VALU cover gather latency),
// 3 rotating slots with hand-unrolled LITERAL slot indices (no dynamic
// indexing -> no scratch), liveness ~124 VGPR under the (256,3) cap ~170.

// Compute tap KK's bilinear weights + issue its 4 gathers into slot S.
#define PREP(KK, S)                                                         \
  {                                                                         \
    float py = off[2 * (KK)] + fhk[(KK) / 3];                               \
    float px = off[2 * (KK) + 1] + fwk[(KK) % 3];                           \
    float y0f = floorf(py);                                                 \
    float x0f = floorf(px);                                                 \
    float wy = py - y0f;                                                    \
    float wx = px - x0f;                                                    \
    int y0 = (int)y0f;                                                      \
    int x0 = (int)x0f;                                                      \
    int y1 = y0 + 1;                                                        \
    int x1 = x0 + 1;                                                        \
    float wy0 = 1.f - wy;                                                   \
    float wx0 = 1.f - wx;                                                   \
    /* validity folded into axis weights: exact 0 products == ref v*valid */\
    float ay0 = ((unsigned)y0 < (unsigned)Hc) ? wy0 : 0.f;                  \
    float ay1 = ((unsigned)y1 < (unsigned)Hc) ? wy : 0.f;                   \
    float ax0 = ((unsigned)x0 < (unsigned)Wc) ? wx0 : 0.f;                  \
    float ax1 = ((unsigned)x1 < (unsigned)Wc) ? wx : 0.f;                   \
    wtb[S][0] = ay0 * ax0;                                                  \
    wtb[S][1] = ay0 * ax1;                                                  \
    wtb[S][2] = ay1 * ax0;                                                  \
    wtb[S][3] = ay1 * ax1;                                                  \
    int y0c = min(max(y0, 0), Hc - 1);                                      \
    int y1c = min(max(y1, 0), Hc - 1);                                      \
    int x0c = min(max(x0, 0), Wc - 1);                                      \
    int x1c = min(max(x1, 0), Wc - 1);                                      \
    vbuf[S][0] = xtb[(y0c << 9) + x0c];                                     \
    vbuf[S][1] = xtb[(y0c << 9) + x1c];                                     \
    vbuf[S][2] = xtb[(y1c << 9) + x0c];                                     \
    vbuf[S][3] = xtb[(y1c << 9) + x1c];                                     \
  }

// Consume slot S for tap KK: bilinear combine + 48-FMA einsum contribution.
#define CONSUME(KK, S)                                                      \
  {                                                                         \
    float w00 = wtb[S][0], w01 = wtb[S][1];                                 \
    float w10 = wtb[S][2], w11 = wtb[S][3];                                 \
    float4 v00 = vbuf[S][0], v01 = vbuf[S][1];                              \
    float4 v10 = vbuf[S][2], v11 = vbuf[S][3];                              \
    float val0 = v00.x * w00 + v01.x * w01 + v10.x * w10 + v11.x * w11;     \
    float val1 = v00.y * w00 + v01.y * w01 + v10.y * w10 + v11.y * w11;     \
    float val2 = v00.z * w00 + v01.z * w01 + v10.z * w10 + v11.z * w11;     \
    const float* wk = weight + (KK);                                        \
    _Pragma("unroll")                                                       \
    for (int o = 0; o < Oc; ++o) {                                          \
      acc[o] = fmaf(wk[o * 27 + 0], val0,                                   \
               fmaf(wk[o * 27 + 9], val1,                                   \
               fmaf(wk[o * 27 + 18], val2, acc[o])));                       \
    }                                                                       \
  }

#define SB __builtin_amdgcn_sched_barrier(0);

__global__ __launch_bounds__(256, 3) void dcn_pipe2(
    const float4* __restrict__ xt,
    const float* __restrict__ offsets,
    const float* __restrict__ weight,
    const float* __restrict__ bias,
    float* __restrict__ out) {
  const int pix = blockIdx.x * 256 + threadIdx.x;
  const int b = pix >> 18;
  const int hw = pix & (HWc - 1);
  const int h = hw >> 9;
  const int w = hw & 511;

  const float4* __restrict__ xtb = xt + ((size_t)b << 18);
  const float* __restrict__ ob = offsets + (size_t)b * (2 * KKc * HWc) + hw;

  // per-tap base coordinates (h-PAD+ky, w-PAD+kx), precomputed once
  float fhk[3], fwk[3];
#pragma unroll
  for (int i = 0; i < 3; ++i) {
    fhk[i] = (float)(h - 1 + i);
    fwk[i] = (float)(w - 1 + i);
  }

  // burst-load all 18 offset planes; consumption of early pairs only needs
  // counted vmcnt waits (later loads stay in flight)
  float off[2 * KKc];
#pragma unroll
  for (int i = 0; i < 2 * KKc; ++i)
    off[i] = __builtin_nontemporal_load(ob + i * HWc);

  float acc[Oc];
#pragma unroll
  for (int o = 0; o < Oc; ++o) acc[o] = bias[o];

  float4 vbuf[3][4];
  float wtb[3][4];

  // depth-2 software pipeline, slots cycle 0,1,2 (all literal)
  PREP(0, 0)
  PREP(1, 1)
  PREP(2, 2) SB CONSUME(0, 0)
  PREP(3, 0) SB CONSUME(1, 1)
  PREP(4, 1) SB CONSUME(2, 2)
  PREP(5, 2) SB CONSUME(3, 0)
  PREP(6, 0) SB CONSUME(4, 1)
  PREP(7, 1) SB CONSUME(5, 2)
  PREP(8, 2) SB CONSUME(6, 0)
  SB CONSUME(7, 1)
  SB CONSUME(8, 2)

  float* op = out + (size_t)b * (Oc * HWc) + hw;
#pragma unroll
  for (int o = 0; o < Oc; ++o)
    __builtin_nontemporal_store(acc[o], &op[o * HWc]);
}

// ---------- fallback (ws too small): single-pass ----------
__global__ __launch_bounds__(256) void dcn_fallback(
    const float* __restrict__ x,
    const float* __restrict__ offsets,
    const float* __restrict__ weight,
    const float* __restrict__ bias,
    float* __restrict__ out) {
  int pix = blockIdx.x * 256 + threadIdx.x;
  int b = pix >> 18;
  int hw = pix & (HWc - 1);
  int h = hw >> 9;
  int w = hw & 511;
  const float* xb = x + b * (Cc * HWc);
  const float* ob = offsets + b * (2 * KKc * HWc) + hw;
  float acc[Oc];
#pragma unroll
  for (int o = 0; o < Oc; ++o) acc[o] = bias[o];
  const float fh = (float)(h - 1);
  const float fw = (float)(w - 1);
#pragma unroll
  for (int kk = 0; kk < KKc; ++kk) {
    const int ky = kk / 3, kx = kk % 3;
    float py = ob[(2 * kk) * HWc] + fh + (float)ky;
    float px = ob[(2 * kk + 1) * HWc] + fw + (float)kx;
    float y0f = floorf(py), x0f = floorf(px);
    float wy = py - y0f, wx = px - x0f;
    int y0 = (int)y0f, x0 = (int)x0f, y1 = y0 + 1, x1 = x0 + 1;
    float wy0 = 1.f - wy, wx0 = 1.f - wx;
    float ay0 = ((unsigned)y0 < (unsigned)Hc) ? wy0 : 0.f;
    float ay1 = ((unsigned)y1 < (unsigned)Hc) ? wy : 0.f;
    float ax0 = ((unsigned)x0 < (unsigned)Wc) ? wx0 : 0.f;
    float ax1 = ((unsigned)x1 < (unsigned)Wc) ? wx : 0.f;
    float w00 = ay0 * ax0, w01 = ay0 * ax1, w10 = ay1 * ax0, w11 = ay1 * ax1;
    int y0c = min(max(y0, 0), Hc - 1);
    int y1c = min(max(y1, 0), Hc - 1);
    int x0c = min(max(x0, 0), Wc - 1);
    int x1c = min(max(x1, 0), Wc - 1);
    int a00 = (y0c << 9) + x0c, a01 = (y0c << 9) + x1c;
    int a10 = (y1c << 9) + x0c, a11 = (y1c << 9) + x1c;
    float val[Cc];
#pragma unroll
    for (int c = 0; c < Cc; ++c) {
      const float* xc = xb + c * HWc;
      val[c] = xc[a00] * w00 + xc[a01] * w01 + xc[a10] * w10 + xc[a11] * w11;
    }
    const float* wk = weight + kk;
#pragma unroll
    for (int o = 0; o < Oc; ++o)
#pragma unroll
      for (int c = 0; c < Cc; ++c)
        acc[o] = fmaf(wk[o * 27 + c * 9], val[c], acc[o]);
  }
  float* op = out + b * (Oc * HWc) + hw;
#pragma unroll
  for (int o = 0; o < Oc; ++o) op[o * HWc] = acc[o];
}

extern "C" void kernel_launch(void* const* d_in, const int* in_sizes, int n_in,
                              void* d_out, int out_size, void* d_ws, size_t ws_size,
                              hipStream_t stream) {
  const float* x = (const float*)d_in[0];
  const float* offsets = (const float*)d_in[1];
  const float* weight = (const float*)d_in[2];
  const float* bias = (const float*)d_in[3];
  float* out = (float*)d_out;

  const int total = Bc * HWc;
  const size_t xt_bytes = (size_t)total * 16;  // 32 MiB

  if (ws_size >= xt_bytes) {
    float4* xt = (float4*)d_ws;
    hipLaunchKernelGGL(transpose_kernel, dim3(total / 256), dim3(256), 0, stream, x, xt);
    hipLaunchKernelGGL(dcn_pipe2, dim3(total / 256), dim3(256), 0, stream,
                       (const float4*)xt, offsets, weight, bias, out);
  } else {
    hipLaunchKernelGGL(dcn_fallback, dim3(total / 256), dim3(256), 0, stream,
                       x, offsets, weight, bias, out);
  }
}

// Round 9
// 434.575 us; speedup vs baseline: 1.0026x; 1.0026x over previous
//
#include <hip/hip_runtime.h>

// FlowGuidedDCN: deformable 3x3 conv, stride=1, pad=1, dilation=1
// x: [B=8, C=3, H=512, W=512] f32 ; offsets: [B,18,H,W] f32 (dy,dx per tap)
// weight: [16,3,3,3] f32 ; bias: [16] f32 ; out: [B,16,H,W] f32

#define Bc 8
#define Cc 3
#define Hc 512
#define Wc 512
#define Oc 16
#define HWc (512 * 512)
#define KKc 9

// ---------- pass 1: x[B,C,H,W] -> xt[B,H,W,4] (channels-last, lane3=0) ----------
__global__ __launch_bounds__(256) void transpose_kernel(
    const float* __restrict__ x, float4* __restrict__ xt) {
  int pix = blockIdx.x * 256 + threadIdx.x;
  int b = pix >> 18;
  int hw = pix & (HWc - 1);
  const float* xb = x + b * (Cc * HWc) + hw;
  float4 v;
  v.x = xb[0];
  v.y = xb[HWc];
  v.z = xb[2 * HWc];
  v.w = 0.f;
  xt[pix] = v;
}

// ---------- pass 2: depth-2 pipelined taps, 3 slots, (256,2) ----------
// History: R7 depth-1 @ (256,2) -> VGPR 108, 158us. R8 depth-2 @ (256,3) ->
// compiler crushed regs to 56, rematerialization doubled VALU, 231us.
// This round: R8's schedule with R7's register freedom. Liveness ~120 VGPR
// (vbuf 48 + off 18 + acc 16 + wtb 12 + misc) — under the 128-reg/4-wave
// occupancy cliff (m69). XCD swizzle: each XCD's 4MiB L2 <- its image's
// 4MiB xt plane, so gathers become L2 hits (shorter latency to hide).

#define PREP(KK, S)                                                         \
  {                                                                         \
    float py = off[2 * (KK)] + fhk[(KK) / 3];                               \
    float px = off[2 * (KK) + 1] + fwk[(KK) % 3];                           \
    float y0f = floorf(py);                                                 \
    float x0f = floorf(px);                                                 \
    float wy = py - y0f;                                                    \
    float wx = px - x0f;                                                    \
    int y0 = (int)y0f;                                                      \
    int x0 = (int)x0f;                                                      \
    int y1 = y0 + 1;                                                        \
    int x1 = x0 + 1;                                                        \
    float wy0 = 1.f - wy;                                                   \
    float wx0 = 1.f - wx;                                                   \
    /* validity folded into axis weights: exact 0 products == ref v*valid */\
    float ay0 = ((unsigned)y0 < (unsigned)Hc) ? wy0 : 0.f;                  \
    float ay1 = ((unsigned)y1 < (unsigned)Hc) ? wy : 0.f;                   \
    float ax0 = ((unsigned)x0 < (unsigned)Wc) ? wx0 : 0.f;                  \
    float ax1 = ((unsigned)x1 < (unsigned)Wc) ? wx : 0.f;                   \
    wtb[S][0] = ay0 * ax0;                                                  \
    wtb[S][1] = ay0 * ax1;                                                  \
    wtb[S][2] = ay1 * ax0;                                                  \
    wtb[S][3] = ay1 * ax1;                                                  \
    int y0c = min(max(y0, 0), Hc - 1);                                      \
    int y1c = min(max(y1, 0), Hc - 1);                                      \
    int x0c = min(max(x0, 0), Wc - 1);                                      \
    int x1c = min(max(x1, 0), Wc - 1);                                      \
    vbuf[S][0] = xtb[(y0c << 9) + x0c];                                     \
    vbuf[S][1] = xtb[(y0c << 9) + x1c];                                     \
    vbuf[S][2] = xtb[(y1c << 9) + x0c];                                     \
    vbuf[S][3] = xtb[(y1c << 9) + x1c];                                     \
  }

#define CONSUME(KK, S)                                                      \
  {                                                                         \
    float w00 = wtb[S][0], w01 = wtb[S][1];                                 \
    float w10 = wtb[S][2], w11 = wtb[S][3];                                 \
    float4 v00 = vbuf[S][0], v01 = vbuf[S][1];                              \
    float4 v10 = vbuf[S][2], v11 = vbuf[S][3];                              \
    float val0 = v00.x * w00 + v01.x * w01 + v10.x * w10 + v11.x * w11;     \
    float val1 = v00.y * w00 + v01.y * w01 + v10.y * w10 + v11.y * w11;     \
    float val2 = v00.z * w00 + v01.z * w01 + v10.z * w10 + v11.z * w11;     \
    const float* wk = weight + (KK);                                        \
    _Pragma("unroll")                                                       \
    for (int o = 0; o < Oc; ++o) {                                          \
      acc[o] = fmaf(wk[o * 27 + 0], val0,                                   \
               fmaf(wk[o * 27 + 9], val1,                                   \
               fmaf(wk[o * 27 + 18], val2, acc[o])));                       \
    }                                                                       \
  }

#define SB __builtin_amdgcn_sched_barrier(0);

__global__ __launch_bounds__(256, 2) void dcn_pipe3(
    const float4* __restrict__ xt,
    const float* __restrict__ offsets,
    const float* __restrict__ weight,
    const float* __restrict__ bias,
    float* __restrict__ out) {
  // XCD swizzle: 8192 blocks round-robin across 8 XCDs; remap so each XCD
  // works one image (its xt plane = 4 MiB = one XCD L2). Bijective (8192%8==0).
  const int bid = blockIdx.x;
  const int swz = ((bid & 7) << 10) + (bid >> 3);
  const int pix = swz * 256 + threadIdx.x;
  const int b = pix >> 18;
  const int hw = pix & (HWc - 1);
  const int h = hw >> 9;
  const int w = hw & 511;

  const float4* __restrict__ xtb = xt + ((size_t)b << 18);
  const float* __restrict__ ob = offsets + (size_t)b * (2 * KKc * HWc) + hw;

  float fhk[3], fwk[3];
#pragma unroll
  for (int i = 0; i < 3; ++i) {
    fhk[i] = (float)(h - 1 + i);
    fwk[i] = (float)(w - 1 + i);
  }

  // burst-load all 18 offset planes (counted vmcnt: early pairs usable while
  // later loads still in flight)
  float off[2 * KKc];
#pragma unroll
  for (int i = 0; i < 2 * KKc; ++i)
    off[i] = __builtin_nontemporal_load(ob + i * HWc);

  float acc[Oc];
#pragma unroll
  for (int o = 0; o < Oc; ++o) acc[o] = bias[o];

  float4 vbuf[3][4];
  float wtb[3][4];

  // depth-2 software pipeline, slots cycle 0,1,2 (all literal indices)
  PREP(0, 0)
  PREP(1, 1)
  PREP(2, 2) SB CONSUME(0, 0)
  PREP(3, 0) SB CONSUME(1, 1)
  PREP(4, 1) SB CONSUME(2, 2)
  PREP(5, 2) SB CONSUME(3, 0)
  PREP(6, 0) SB CONSUME(4, 1)
  PREP(7, 1) SB CONSUME(5, 2)
  PREP(8, 2) SB CONSUME(6, 0)
  SB CONSUME(7, 1)
  SB CONSUME(8, 2)

  float* op = out + (size_t)b * (Oc * HWc) + hw;
#pragma unroll
  for (int o = 0; o < Oc; ++o)
    __builtin_nontemporal_store(acc[o], &op[o * HWc]);
}

// ---------- fallback (ws too small): single-pass ----------
__global__ __launch_bounds__(256) void dcn_fallback(
    const float* __restrict__ x,
    const float* __restrict__ offsets,
    const float* __restrict__ weight,
    const float* __restrict__ bias,
    float* __restrict__ out) {
  int pix = blockIdx.x * 256 + threadIdx.x;
  int b = pix >> 18;
  int hw = pix & (HWc - 1);
  int h = hw >> 9;
  int w = hw & 511;
  const float* xb = x + b * (Cc * HWc);
  const float* ob = offsets + b * (2 * KKc * HWc) + hw;
  float acc[Oc];
#pragma unroll
  for (int o = 0; o < Oc; ++o) acc[o] = bias[o];
  const float fh = (float)(h - 1);
  const float fw = (float)(w - 1);
#pragma unroll
  for (int kk = 0; kk < KKc; ++kk) {
    const int ky = kk / 3, kx = kk % 3;
    float py = ob[(2 * kk) * HWc] + fh + (float)ky;
    float px = ob[(2 * kk + 1) * HWc] + fw + (float)kx;
    float y0f = floorf(py), x0f = floorf(px);
    float wy = py - y0f, wx = px - x0f;
    int y0 = (int)y0f, x0 = (int)x0f, y1 = y0 + 1, x1 = x0 + 1;
    float wy0 = 1.f - wy, wx0 = 1.f - wx;
    float ay0 = ((unsigned)y0 < (unsigned)Hc) ? wy0 : 0.f;
    float ay1 = ((unsigned)y1 < (unsigned)Hc) ? wy : 0.f;
    float ax0 = ((unsigned)x0 < (unsigned)Wc) ? wx0 : 0.f;
    float ax1 = ((unsigned)x1 < (unsigned)Wc) ? wx : 0.f;
    float w00 = ay0 * ax0, w01 = ay0 * ax1, w10 = ay1 * ax0, w11 = ay1 * ax1;
    int y0c = min(max(y0, 0), Hc - 1);
    int y1c = min(max(y1, 0), Hc - 1);
    int x0c = min(max(x0, 0), Wc - 1);
    int x1c = min(max(x1, 0), Wc - 1);
    int a00 = (y0c << 9) + x0c, a01 = (y0c << 9) + x1c;
    int a10 = (y1c << 9) + x0c, a11 = (y1c << 9) + x1c;
    float val[Cc];
#pragma unroll
    for (int c = 0; c < Cc; ++c) {
      const float* xc = xb + c * HWc;
      val[c] = xc[a00] * w00 + xc[a01] * w01 + xc[a10] * w10 + xc[a11] * w11;
    }
    const float* wk = weight + kk;
#pragma unroll
    for (int o = 0; o < Oc; ++o)
#pragma unroll
      for (int c = 0; c < Cc; ++c)
        acc[o] = fmaf(wk[o * 27 + c * 9], val[c], acc[o]);
  }
  float* op = out + b * (Oc * HWc) + hw;
#pragma unroll
  for (int o = 0; o < Oc; ++o) op[o * HWc] = acc[o];
}

extern "C" void kernel_launch(void* const* d_in, const int* in_sizes, int n_in,
                              void* d_out, int out_size, void* d_ws, size_t ws_size,
                              hipStream_t stream) {
  const float* x = (const float*)d_in[0];
  const float* offsets = (const float*)d_in[1];
  const float* weight = (const float*)d_in[2];
  const float* bias = (const float*)d_in[3];
  float* out = (float*)d_out;

  const int total = Bc * HWc;
  const size_t xt_bytes = (size_t)total * 16;  // 32 MiB

  if (ws_size >= xt_bytes) {
    float4* xt = (float4*)d_ws;
    hipLaunchKernelGGL(transpose_kernel, dim3(total / 256), dim3(256), 0, stream, x, xt);
    hipLaunchKernelGGL(dcn_pipe3, dim3(total / 256), dim3(256), 0, stream,
                       (const float4*)xt, offsets, weight, bias, out);
  } else {
    hipLaunchKernelGGL(dcn_fallback, dim3(total / 256), dim3(256), 0, stream,
                       x, offsets, weight, bias, out);
  }
}